// Round 16
// baseline (30.934 us; speedup 1.0000x reference)
//
#include <hip/hip_runtime.h>
#include <math.h>

// Problem constants
#define BB 512      // batch (edges)
#define NN 4096     // nodes
#define LL 128      // feature dim
#define IN_DIM 385  // 3*L + ND
#define NK8_1 49    // ceil(IN_DIM/8) k-groups, layer 1 (8 bf16 per 16B load)
#define NK8_2 16    // LL/8 k-groups, layer 2 / GRU
#define EPB 4       // edges per block (edge kernel)
#define TASKS 1024  // 2*BB
#define GPB 4       // nodes per block (gru kernel)

// ---------------------------------------------------------------------------
// Workspace layout (float/int offsets; uint4 regions 16B-aligned)
// ---------------------------------------------------------------------------
#define OFF_MSGS  0                            // msgs[task][LL] f32 (dense)
#define OFF_HEAD  (OFF_MSGS + TASKS * LL)      // head[node] int (-1 init)
#define OFF_NEXT  (OFF_HEAD + NN)              // next[task] int
#define OFF_COUNT (OFF_NEXT + TASKS)           // seen_count (1 int) + pad
#define OFF_LIST  (OFF_COUNT + 4)              // seen list (1024 ints)
#define OFF_W1BS  (OFF_LIST + 1024)            // src w1 bf16 uint4[k8*128+j]
#define OFF_W1BT  (OFF_W1BS + NK8_1 * LL * 4)
#define OFF_W2BS  (OFF_W1BT + NK8_1 * LL * 4)
#define OFF_W2BT  (OFF_W2BS + NK8_2 * LL * 4)
#define OFF_WIHB  (OFF_W2BT + NK8_2 * LL * 4)  // uint4[(gate*16+k8)*128+j]
#define OFF_WHHB  (OFF_WIHB + 3 * NK8_2 * LL * 4)

// ---------------------------------------------------------------------------
// bf16 helpers
// ---------------------------------------------------------------------------
__device__ inline unsigned short f2bf(float f) {          // RNE round
    unsigned u = __float_as_uint(f);
    return (unsigned short)((u + 0x7fffu + ((u >> 16) & 1u)) >> 16);
}
__device__ inline unsigned pack2(float lo, float hi) {
    return (unsigned)f2bf(lo) | ((unsigned)f2bf(hi) << 16);
}
struct f8 { float v[8]; };
__device__ inline f8 unpack8(uint4 u) {                   // 8 bf16 -> f32
    f8 r;
    r.v[0] = __uint_as_float(u.x << 16); r.v[1] = __uint_as_float(u.x & 0xffff0000u);
    r.v[2] = __uint_as_float(u.y << 16); r.v[3] = __uint_as_float(u.y & 0xffff0000u);
    r.v[4] = __uint_as_float(u.z << 16); r.v[5] = __uint_as_float(u.z & 0xffff0000u);
    r.v[6] = __uint_as_float(u.w << 16); r.v[7] = __uint_as_float(u.w & 0xffff0000u);
    return r;
}

// ---------------------------------------------------------------------------
// Prep (minimal critical path): head[-1] fill + bf16-pack w1 and w2 only.
// ---------------------------------------------------------------------------
__global__ __launch_bounds__(256) void prep_kernel(
    const float* __restrict__ sw1, const float* __restrict__ tw1,
    const float* __restrict__ sw2, const float* __restrict__ tw2,
    float* __restrict__ ws)
{
    const int i = blockIdx.x * 256 + threadIdx.x;
    const int stride = gridDim.x * 256;

    int* heads = (int*)ws + OFF_HEAD;
    for (int idx = i; idx < NN; idx += stride)
        heads[idx] = -1;
    if (i == 0)
        ((int*)ws)[OFF_COUNT] = 0;

    // layer-1: (L, IN=385) -> bf16x8 blocks, zero-padded to 392
    uint4* w1bs = (uint4*)(ws + OFF_W1BS);
    uint4* w1bt = (uint4*)(ws + OFF_W1BT);
    for (int idx = i; idx < NK8_1 * LL; idx += stride) {
        const int k8 = idx >> 7, j = idx & 127;
        const int k = k8 * 8;
        float a[8], b[8];
        #pragma unroll
        for (int c = 0; c < 8; ++c) {
            a[c] = (k + c < IN_DIM) ? sw1[j * IN_DIM + k + c] : 0.f;
            b[c] = (k + c < IN_DIM) ? tw1[j * IN_DIM + k + c] : 0.f;
        }
        w1bs[idx] = make_uint4(pack2(a[0], a[1]), pack2(a[2], a[3]),
                               pack2(a[4], a[5]), pack2(a[6], a[7]));
        w1bt[idx] = make_uint4(pack2(b[0], b[1]), pack2(b[2], b[3]),
                               pack2(b[4], b[5]), pack2(b[6], b[7]));
    }
    // layer-2: (L, L)
    uint4* w2bs = (uint4*)(ws + OFF_W2BS);
    uint4* w2bt = (uint4*)(ws + OFF_W2BT);
    for (int idx = i; idx < NK8_2 * LL; idx += stride) {
        const int k8 = idx >> 7, j = idx & 127;
        const int k = k8 * 8;
        const float* pa = sw2 + j * LL + k;
        const float* pb = tw2 + j * LL + k;
        w2bs[idx] = make_uint4(pack2(pa[0], pa[1]), pack2(pa[2], pa[3]),
                               pack2(pa[4], pa[5]), pack2(pa[6], pa[7]));
        w2bt[idx] = make_uint4(pack2(pb[0], pb[1]), pack2(pb[2], pb[3]),
                               pack2(pb[4], pb[5]), pack2(pb[6], pb[7]));
    }
}

// One bf16x8 weight block against FOUR edges' 8 input floats each.
#define BF8_STEP4(WU, P0, P1, P2, P3, OFS) {                            \
    const f8 W_ = unpack8(WU);                                          \
    const float4 A0 = *(const float4*)((P0) + (OFS));                   \
    const float4 A1 = *(const float4*)((P0) + (OFS) + 4);               \
    const float4 B0 = *(const float4*)((P1) + (OFS));                   \
    const float4 B1 = *(const float4*)((P1) + (OFS) + 4);               \
    const float4 C0 = *(const float4*)((P2) + (OFS));                   \
    const float4 C1 = *(const float4*)((P2) + (OFS) + 4);               \
    const float4 D0 = *(const float4*)((P3) + (OFS));                   \
    const float4 D1 = *(const float4*)((P3) + (OFS) + 4);               \
    a0 = fmaf(W_.v[0], A0.x, a0); a1 = fmaf(W_.v[0], B0.x, a1);         \
    a2 = fmaf(W_.v[0], C0.x, a2); a3 = fmaf(W_.v[0], D0.x, a3);         \
    a0 = fmaf(W_.v[1], A0.y, a0); a1 = fmaf(W_.v[1], B0.y, a1);         \
    a2 = fmaf(W_.v[1], C0.y, a2); a3 = fmaf(W_.v[1], D0.y, a3);         \
    a0 = fmaf(W_.v[2], A0.z, a0); a1 = fmaf(W_.v[2], B0.z, a1);         \
    a2 = fmaf(W_.v[2], C0.z, a2); a3 = fmaf(W_.v[2], D0.z, a3);         \
    a0 = fmaf(W_.v[3], A0.w, a0); a1 = fmaf(W_.v[3], B0.w, a1);         \
    a2 = fmaf(W_.v[3], C0.w, a2); a3 = fmaf(W_.v[3], D0.w, a3);         \
    a0 = fmaf(W_.v[4], A1.x, a0); a1 = fmaf(W_.v[4], B1.x, a1);         \
    a2 = fmaf(W_.v[4], C1.x, a2); a3 = fmaf(W_.v[4], D1.x, a3);         \
    a0 = fmaf(W_.v[5], A1.y, a0); a1 = fmaf(W_.v[5], B1.y, a1);         \
    a2 = fmaf(W_.v[5], C1.y, a2); a3 = fmaf(W_.v[5], D1.y, a3);         \
    a0 = fmaf(W_.v[6], A1.z, a0); a1 = fmaf(W_.v[6], B1.z, a1);         \
    a2 = fmaf(W_.v[6], C1.z, a2); a3 = fmaf(W_.v[6], D1.z, a3);         \
    a0 = fmaf(W_.v[7], A1.w, a0); a1 = fmaf(W_.v[7], B1.w, a1);         \
    a2 = fmaf(W_.v[7], C1.w, a2); a3 = fmaf(W_.v[7], D1.w, a3); }

// ---------------------------------------------------------------------------
// Edge messages: EPB=4, 512 threads (4 k-groups x 128 features), 256 edge
// blocks. Blocks 256..279: GRU weight bf16-pack (consumed by kernel 3).
// NO copy blocks here anymore (copy moved to the GRU dispatch, spread wide).
// ---------------------------------------------------------------------------
__global__ __launch_bounds__(512) void edge_msg_kernel(
    const float* __restrict__ x,        // (B, N, 1)
    const float* __restrict__ memory,   // (N, L)
    const float* __restrict__ delta_t,  // (B, N, L)
    const float* __restrict__ sb1, const float* __restrict__ sb2,
    const float* __restrict__ tb1, const float* __restrict__ tb2,
    const float* __restrict__ wih, const float* __restrict__ whh,
    const int* __restrict__ source, const int* __restrict__ target,
    float* __restrict__ ws, float* __restrict__ out)
{
    const int tid = threadIdx.x;

    if (blockIdx.x >= 256) {
        // ---- GRU weight bf16-pack (24 x 512 = 12288 = 2*3*16*128) ----
        const int idx = (blockIdx.x - 256) * 512 + tid;  // [0, 12288)
        const int half = idx >= 6144;                    // 0: wih, 1: whh
        const int id2 = idx - half * 6144;
        const int j = id2 & 127;
        const int gk = id2 >> 7;             // gate*16 + k8
        const int gate = gk >> 4, k8 = gk & 15;
        const float* p = (half ? whh : wih) + (gate * LL + j) * LL + k8 * 8;
        uint4* dst = (uint4*)(ws + (half ? OFF_WHHB : OFF_WIHB));
        dst[id2] = make_uint4(pack2(p[0], p[1]), pack2(p[2], p[3]),
                              pack2(p[4], p[5]), pack2(p[6], p[7]));
        return;
    }

    // ---- edge blocks: 4 edges, one side ----
    const int side  = blockIdx.x & 1;
    const int chunk = blockIdx.x >> 1;       // 0..127
    const int g     = tid >> 7;              // k-split group 0..3
    const int j     = tid & 127;             // output feature

    int eg[EPB], nodev[EPB], otherv[EPB];
    #pragma unroll
    for (int e = 0; e < EPB; ++e) {
        eg[e] = chunk * EPB + e;
        const int s = source[eg[e]], t = target[eg[e]];
        nodev[e]  = side ? t : s;
        otherv[e] = side ? s : t;
    }

    __shared__ float h1s[EPB][LL];
    __shared__ float part1[4][EPB][LL];
    __shared__ float part2[4][EPB][LL];

    const uint4* w1b = (const uint4*)(ws + (side ? OFF_W1BT : OFF_W1BS));
    const uint4* w2b = (const uint4*)(ws + (side ? OFF_W2BT : OFF_W2BS));
    const float* b1  = side ? tb1 : sb1;
    const float* b2  = side ? tb2 : sb2;

    const float* n0 = memory + (size_t)nodev[0] * LL;
    const float* n1 = memory + (size_t)nodev[1] * LL;
    const float* n2 = memory + (size_t)nodev[2] * LL;
    const float* n3 = memory + (size_t)nodev[3] * LL;
    const float* o0 = memory + (size_t)otherv[0] * LL;
    const float* o1 = memory + (size_t)otherv[1] * LL;
    const float* o2 = memory + (size_t)otherv[2] * LL;
    const float* o3 = memory + (size_t)otherv[3] * LL;
    const float* d0 = delta_t + ((size_t)eg[0] * NN + nodev[0]) * LL;
    const float* d1 = delta_t + ((size_t)eg[1] * NN + nodev[1]) * LL;
    const float* d2 = delta_t + ((size_t)eg[2] * NN + nodev[2]) * LL;
    const float* d3 = delta_t + ((size_t)eg[3] * NN + nodev[3]) * LL;

    // Layer 1, k8 segments: [0,16)=mem[node], [16,32)=mem[other],
    // [32,48)=delta_t, 48=x. Groups: g0 [0,12), g1 [12,24), g2 [24,36),
    // g3 [36,49) -- 12/12/12/13.
    {
        float a0 = 0.f, a1 = 0.f, a2 = 0.f, a3 = 0.f;
        if (g == 0) {
            #pragma unroll 4
            for (int k8 = 0; k8 < 12; ++k8) {
                const uint4 wu = w1b[k8 * LL + j];
                BF8_STEP4(wu, n0, n1, n2, n3, 8 * k8)
            }
        } else if (g == 1) {
            #pragma unroll 4
            for (int k8 = 12; k8 < 16; ++k8) {
                const uint4 wu = w1b[k8 * LL + j];
                BF8_STEP4(wu, n0, n1, n2, n3, 8 * k8)
            }
            #pragma unroll 4
            for (int k8 = 16; k8 < 24; ++k8) {
                const uint4 wu = w1b[k8 * LL + j];
                BF8_STEP4(wu, o0, o1, o2, o3, 8 * k8 - 128)
            }
        } else if (g == 2) {
            #pragma unroll 4
            for (int k8 = 24; k8 < 32; ++k8) {
                const uint4 wu = w1b[k8 * LL + j];
                BF8_STEP4(wu, o0, o1, o2, o3, 8 * k8 - 128)
            }
            #pragma unroll 4
            for (int k8 = 32; k8 < 36; ++k8) {
                const uint4 wu = w1b[k8 * LL + j];
                BF8_STEP4(wu, d0, d1, d2, d3, 8 * k8 - 256)
            }
        } else {
            #pragma unroll 4
            for (int k8 = 36; k8 < 48; ++k8) {
                const uint4 wu = w1b[k8 * LL + j];
                BF8_STEP4(wu, d0, d1, d2, d3, 8 * k8 - 256)
            }
            {   // k8 = 48: k=384 is x; 385..391 zero-padded weights
                const uint4 wu = w1b[48 * LL + j];
                const float w0 = __uint_as_float(wu.x << 16);
                a0 = fmaf(w0, x[(size_t)eg[0] * NN + nodev[0]], a0);
                a1 = fmaf(w0, x[(size_t)eg[1] * NN + nodev[1]], a1);
                a2 = fmaf(w0, x[(size_t)eg[2] * NN + nodev[2]], a2);
                a3 = fmaf(w0, x[(size_t)eg[3] * NN + nodev[3]], a3);
            }
        }
        part1[g][0][j] = a0; part1[g][1][j] = a1;
        part1[g][2][j] = a2; part1[g][3][j] = a3;
    }
    __syncthreads();

    // Combine + bias + relu; group g finishes edge e=g.
    h1s[g][j] = fmaxf(part1[0][g][j] + part1[1][g][j]
                    + part1[2][g][j] + part1[3][g][j] + b1[j], 0.0f);
    __syncthreads();

    // Layer 2: group g -> k8 [4g, 4g+4)
    {
        const int k80 = g * 4, k81 = k80 + 4;
        float a0 = 0.f, a1 = 0.f, a2 = 0.f, a3 = 0.f;
        #pragma unroll 4
        for (int k8 = k80; k8 < k81; ++k8) {
            const uint4 wu = w2b[k8 * LL + j];
            BF8_STEP4(wu, &h1s[0][0], &h1s[1][0], &h1s[2][0], &h1s[3][0], 8 * k8)
        }
        part2[g][0][j] = a0; part2[g][1][j] = a1;
        part2[g][2][j] = a2; part2[g][3][j] = a3;
    }
    __syncthreads();

    // DENSE message write; group g finishes edge e=g.
    {
        const int task = side * BB + eg[g];
        const float m = part2[0][g][j] + part2[1][g][j]
                      + part2[2][g][j] + part2[3][g][j] + b2[j];
        ws[OFF_MSGS + (size_t)task * LL + j] = m;
    }
    // Chain-link + first-toucher compaction (one exch per task).
    if (tid < EPB) {
        const int node = nodev[tid];
        const int task = side * BB + eg[tid];
        const int old = atomicExch((int*)ws + OFF_HEAD + node, task);
        ((int*)ws)[OFF_NEXT + task] = old;
        if (old == -1) {
            const int pos = atomicAdd((int*)ws + OFF_COUNT, 1);
            ((int*)ws)[OFF_LIST + pos] = node;
        }
    }
}

// ---------------------------------------------------------------------------
// GRU dispatch: phase 0 = copy UNSEEN rows (head==-1), spread over ALL 256
// blocks (16 nodes each -- disjoint from GRU-written seen rows, no race);
// then GRU over the compact seen list (GPB=4, gate-split, chains, bf16).
// ---------------------------------------------------------------------------
__global__ __launch_bounds__(256) void gru_kernel(
    const float* __restrict__ memory,
    const float* __restrict__ bih, const float* __restrict__ bhh,
    const float* __restrict__ ws, float* __restrict__ out)
{
    const int tid = threadIdx.x;
    const int g = tid >> 7, j = tid & 127;

    const int* heads = (const int*)ws + OFF_HEAD;
    const int* nexts = (const int*)ws + OFF_NEXT;

    // ---- Phase 0: passthrough copy of this block's 16 unseen rows ----
    {
        const int f4i = tid & 31;            // float4 index within row
        #pragma unroll
        for (int r = 0; r < 2; ++r) {
            const int node = blockIdx.x * 16 + r * 8 + (tid >> 5);
            if (heads[node] == -1)
                ((float4*)out)[(size_t)node * 32 + f4i] =
                    ((const float4*)memory)[(size_t)node * 32 + f4i];
        }
    }

    // ---- Phase 1: GRU over the seen list ----
    const int scount = ((const int*)ws)[OFF_COUNT];
    const int base = blockIdx.x * GPB;
    if (base >= scount) return;
    const int nact = min(GPB, scount - base);

    __shared__ float ah[2 * GPB][LL];        // [slot]=agg rows, [GPB+slot]=h
    __shared__ float gates[6][GPB][LL];      // 12 KB
    __shared__ int   nodes_sh[GPB];

    int nd[GPB];
    #pragma unroll
    for (int s = 0; s < GPB; ++s)
        nd[s] = (base + s < scount) ? ((const int*)ws)[OFF_LIST + base + s]
                                    : ((const int*)ws)[OFF_LIST + base];
    if (tid < GPB) nodes_sh[tid] = nd[tid];

    // Stage operands: g0 walks chains -> agg; g1 loads h rows.
    if (g == 0) {
        #pragma unroll
        for (int s = 0; s < GPB; ++s) {
            float acc = 0.0f;
            int c = 0;
            for (int t = heads[nd[s]]; t != -1; t = nexts[t]) {
                acc += ws[OFF_MSGS + (size_t)t * LL + j];
                ++c;
            }
            ah[s][j] = acc / (float)c;       // c >= 1 (listed node)
        }
    } else {
        #pragma unroll
        for (int s = 0; s < GPB; ++s)
            ah[GPB + s][j] = memory[(size_t)nd[s] * LL + j];
    }
    __syncthreads();

    // Gate-split matvec: g0 -> wih vs agg, g1 -> whh vs h (LDS rows).
    const uint4* wpb = (const uint4*)(ws + (g ? OFF_WHHB : OFF_WIHB));
    float a0[GPB] = {}, a1[GPB] = {}, a2[GPB] = {};
    #pragma unroll 2
    for (int k8 = 0; k8 < NK8_2; ++k8) {
        const f8 w0 = unpack8(wpb[(0 * NK8_2 + k8) * LL + j]);
        const f8 w1 = unpack8(wpb[(1 * NK8_2 + k8) * LL + j]);
        const f8 w2 = unpack8(wpb[(2 * NK8_2 + k8) * LL + j]);
        #pragma unroll
        for (int s = 0; s < GPB; ++s) {
            const float4 v0 = *(const float4*)&ah[g * GPB + s][8 * k8];
            const float4 v1 = *(const float4*)&ah[g * GPB + s][8 * k8 + 4];
            const float v[8] = {v0.x, v0.y, v0.z, v0.w, v1.x, v1.y, v1.z, v1.w};
            #pragma unroll
            for (int c = 0; c < 8; ++c) {
                a0[s] = fmaf(w0.v[c], v[c], a0[s]);
                a1[s] = fmaf(w1.v[c], v[c], a1[s]);
                a2[s] = fmaf(w2.v[c], v[c], a2[s]);
            }
        }
    }
    #pragma unroll
    for (int s = 0; s < GPB; ++s) {
        gates[g * 3 + 0][s][j] = a0[s];
        gates[g * 3 + 1][s][j] = a1[s];
        gates[g * 3 + 2][s][j] = a2[s];
    }
    __syncthreads();

    // Finalize; h from LDS.
    const int total = nact * LL;
    for (int o = tid; o < total; o += 256) {
        const int s = o >> 7, jj = o & 127;
        const int node = nodes_sh[s];
        const float ir = gates[0][s][jj] + bih[jj];
        const float iz = gates[1][s][jj] + bih[LL + jj];
        const float inn = gates[2][s][jj] + bih[2 * LL + jj];
        const float hr = gates[3][s][jj] + bhh[jj];
        const float hz = gates[4][s][jj] + bhh[LL + jj];
        const float hn = gates[5][s][jj] + bhh[2 * LL + jj];
        const float r = 1.0f / (1.0f + __expf(-(ir + hr)));
        const float z = 1.0f / (1.0f + __expf(-(iz + hz)));
        const float n = tanhf(inn + r * hn);
        const float h = ah[GPB + s][jj];
        out[(size_t)node * LL + jj] = (1.0f - z) * n + z * h;
    }
}

// ---------------------------------------------------------------------------
extern "C" void kernel_launch(void* const* d_in, const int* in_sizes, int n_in,
                              void* d_out, int out_size, void* d_ws, size_t ws_size,
                              hipStream_t stream) {
    const float* x        = (const float*)d_in[0];
    const float* memory   = (const float*)d_in[1];
    const float* delta_t  = (const float*)d_in[2];
    const float* src_w1   = (const float*)d_in[3];
    const float* src_b1   = (const float*)d_in[4];
    const float* src_w2   = (const float*)d_in[5];
    const float* src_b2   = (const float*)d_in[6];
    const float* tar_w1   = (const float*)d_in[7];
    const float* tar_b1   = (const float*)d_in[8];
    const float* tar_w2   = (const float*)d_in[9];
    const float* tar_b2   = (const float*)d_in[10];
    const float* gru_wih  = (const float*)d_in[11];
    const float* gru_whh  = (const float*)d_in[12];
    const float* gru_bih  = (const float*)d_in[13];
    const float* gru_bhh  = (const float*)d_in[14];
    const int*   source   = (const int*)d_in[15];
    const int*   target   = (const int*)d_in[16];

    float* out = (float*)d_out;
    float* ws  = (float*)d_ws;

    // 1) prep: head fill + w1/w2 bf16-pack (edge prereqs only)
    prep_kernel<<<128, 256, 0, stream>>>(
        src_w1, tar_w1, src_w2, tar_w2, ws);

    // 2) edge messages (256 blocks, EPB=4) + gru weight pack (24 blocks)
    edge_msg_kernel<<<280, 512, 0, stream>>>(
        x, memory, delta_t, src_b1, src_b2, tar_b1, tar_b2,
        gru_wih, gru_whh, source, target, ws, out);

    // 3) GRU + unseen-row copy, spread over 256 blocks
    gru_kernel<<<256, 256, 0, stream>>>(
        memory, gru_bih, gru_bhh, ws, out);
}